// Round 5
// baseline (188.957 us; speedup 1.0000x reference)
//
#include <hip/hip_runtime.h>
#include <math.h>

#define B_ 128
#define N_ 100
#define E_ 100
#define D_ 64
#define EH 25        // quarter of e (or n) per block
#define PAD 68       // row pad (f32 words) for [*][D] tiles
#define SP 28        // score/mask row pad (f32 words), mult of 4
#define KP 28        // u8 mask row pad
#define LALPHA 0.2f
#define NEGV -9e15f

__device__ __forceinline__ float4 ld4(const float* p) { return *reinterpret_cast<const float4*>(p); }
__device__ __forceinline__ void st4(float* p, float4 v) { *reinterpret_cast<float4*>(p) = v; }
__device__ __forceinline__ float dot4(float4 a, float4 b) {
    return a.x * b.x + a.y * b.y + a.z * b.z + a.w * b.w;
}

// ---------------------------------------------------------------------------
// node -> edge. grid (4, B), 256 threads, ~48KB LDS -> 2 blocks/CU.
//   ec[e,d]  = sum_n (H>0) h[n,d]         (e in this block's quarter)
//   S[n,e]   = select_k( sum_d h[n,d]*ec[e,d]*a_k[d] ), leaky, NEG
//   P        = softmax_n(S);  edge[e,d] = sum_n P[n,e] h[n,d]
// sh_S doubles as m01 (mask floats) before phase C.
// ---------------------------------------------------------------------------
__global__ __launch_bounds__(256, 4) void k_n2e(
    const float* __restrict__ h,   // (B,N,D)
    const float* __restrict__ Hm,  // (B,N,E)
    const float* __restrict__ a0,
    const float* __restrict__ a1,
    const float* __restrict__ a2,
    float* __restrict__ edge)      // (B,E,D)
{
    __shared__ float sh_h[N_ * PAD];          // 27.2 KB
    __shared__ float sh_ec[EH * PAD];         //  6.8 KB
    __shared__ float sh_S[N_ * SP];           // 11.2 KB (m01 -> scores -> P)
    __shared__ unsigned char sh_k[N_ * KP];   //  2.8 KB
    __shared__ float sh_a[3 * PAD];           //  0.8 KB
    __shared__ float sh_inv[EH];

    const int b = blockIdx.y;
    const int e_base = blockIdx.x * EH;
    const int tid = threadIdx.x;

    // ---- A: stage ----
    for (int i4 = tid; i4 < N_ * D_ / 4; i4 += 256) {
        const float4 v = ld4(&h[b * N_ * D_ + i4 * 4]);
        st4(&sh_h[(i4 >> 4) * PAD + (i4 & 15) * 4], v);
    }
    if (tid < 192) {
        const int k = tid >> 6, d = tid & 63;
        sh_a[k * PAD + d] = (k == 0 ? a0 : k == 1 ? a1 : a2)[d];
    }
    for (int i = tid; i < N_ * EH; i += 256) {
        const int n = i / EH, le = i % EH;
        const int kk = (int)Hm[(b * N_ + n) * E_ + e_base + le];
        sh_k[n * KP + le] = (unsigned char)kk;
        sh_S[n * SP + le] = (kk > 0) ? 1.f : 0.f;   // m01 (aliased)
    }
    __syncthreads();

    // ---- B: ec[e,d] = sum_n m01[n,e]*h[n,d]; tile (4e,8d), 4-way n-split; 224 thr ----
    if (tid < 224) {
        const int ng = tid & 3, t4 = tid >> 2;
        const int dg = t4 & 7, eg = t4 >> 3;        // eg 0..6
        const int e0 = eg * 4, d0 = dg * 8;
        float acc[4][8];
        #pragma unroll
        for (int i = 0; i < 4; ++i)
            #pragma unroll
            for (int j = 0; j < 8; ++j) acc[i][j] = 0.f;
        #pragma unroll 5
        for (int n = ng * 25; n < ng * 25 + 25; ++n) {
            const float4 m  = ld4(&sh_S[n * SP + e0]);
            const float4 h0 = ld4(&sh_h[n * PAD + d0]);
            const float4 h1 = ld4(&sh_h[n * PAD + d0 + 4]);
            const float mv[4] = {m.x, m.y, m.z, m.w};
            const float hv[8] = {h0.x, h0.y, h0.z, h0.w, h1.x, h1.y, h1.z, h1.w};
            #pragma unroll
            for (int i = 0; i < 4; ++i)
                #pragma unroll
                for (int j = 0; j < 8; ++j) acc[i][j] += mv[i] * hv[j];
        }
        #pragma unroll
        for (int i = 0; i < 4; ++i)
            #pragma unroll
            for (int j = 0; j < 8; ++j) {
                float v = acc[i][j];
                v += __shfl_xor(v, 1);
                v += __shfl_xor(v, 2);
                acc[i][j] = v;
            }
        if (ng == 0) {
            #pragma unroll
            for (int i = 0; i < 4; ++i)
                if (e0 + i < EH) {
                    float* dst = &sh_ec[(e0 + i) * PAD + d0];
                    st4(dst,     make_float4(acc[i][0], acc[i][1], acc[i][2], acc[i][3]));
                    st4(dst + 4, make_float4(acc[i][4], acc[i][5], acc[i][6], acc[i][7]));
                }
        }
    }
    __syncthreads();

    // ---- C: scores; rows {ng+25i} x 5 cols, d halves; 250 thr ----
    if (tid < 250) {
        const int t2 = tid >> 1, dh = tid & 1;
        const int cg = t2 / 25, ng = t2 % 25;       // cg 0..4
        const int e0 = cg * 5;
        float acc[3][4][5];
        #pragma unroll
        for (int k = 0; k < 3; ++k)
            #pragma unroll
            for (int i = 0; i < 4; ++i)
                #pragma unroll
                for (int j = 0; j < 5; ++j) acc[k][i][j] = 0.f;
        const int dbase = dh * 32;
        #pragma unroll 2
        for (int s = 0; s < 8; ++s) {
            const int d0 = dbase + s * 4;
            float4 hv[4], av[3];
            #pragma unroll
            for (int i = 0; i < 4; ++i) hv[i] = ld4(&sh_h[(ng + 25 * i) * PAD + d0]);
            #pragma unroll
            for (int k = 0; k < 3; ++k) av[k] = ld4(&sh_a[k * PAD + d0]);
            #pragma unroll
            for (int j = 0; j < 5; ++j) {
                const float4 ev = ld4(&sh_ec[(e0 + j) * PAD + d0]);
                #pragma unroll
                for (int k = 0; k < 3; ++k) {
                    const float4 w = make_float4(ev.x * av[k].x, ev.y * av[k].y,
                                                 ev.z * av[k].z, ev.w * av[k].w);
                    #pragma unroll
                    for (int i = 0; i < 4; ++i) acc[k][i][j] += dot4(hv[i], w);
                }
            }
        }
        #pragma unroll
        for (int k = 0; k < 3; ++k)
            #pragma unroll
            for (int i = 0; i < 4; ++i)
                #pragma unroll
                for (int j = 0; j < 5; ++j)
                    acc[k][i][j] += __shfl_xor(acc[k][i][j], 1);
        #define EPI_N2E(I) { \
            _Pragma("unroll") \
            for (int j = 0; j < 5; ++j) { \
                const int kk = sh_k[(ng + 25 * (I)) * KP + e0 + j]; \
                const float v = (kk == 1) ? acc[0][I][j] : (kk == 2) ? acc[1][I][j] : acc[2][I][j]; \
                const float lv = (v >= 0.f) ? v : LALPHA * v; \
                sh_S[(ng + 25 * (I)) * SP + e0 + j] = kk ? lv : NEGV; } }
        if (dh == 0) { EPI_N2E(0); EPI_N2E(1); } else { EPI_N2E(2); EPI_N2E(3); }
        #undef EPI_N2E
    }
    __syncthreads();

    // ---- D: softmax over n per e-column; 8 lanes/column; 200 thr ----
    if (tid < 200) {
        const int le = tid >> 3, g = tid & 7;
        float mx = -INFINITY;
        for (int n = g; n < N_; n += 8) mx = fmaxf(mx, sh_S[n * SP + le]);
        mx = fmaxf(mx, __shfl_xor(mx, 1));
        mx = fmaxf(mx, __shfl_xor(mx, 2));
        mx = fmaxf(mx, __shfl_xor(mx, 4));
        float sum = 0.f;
        for (int n = g; n < N_; n += 8) {
            const float p = __expf(sh_S[n * SP + le] - mx);
            sh_S[n * SP + le] = p;
            sum += p;
        }
        sum += __shfl_xor(sum, 1);
        sum += __shfl_xor(sum, 2);
        sum += __shfl_xor(sum, 4);
        if (g == 0) sh_inv[le] = 1.f / sum;
    }
    __syncthreads();

    // ---- E: edge[e,d] = inv[e]*sum_n P[n,e] h[n,d]; tile (4e,8d), n-split-4; 224 thr ----
    if (tid < 224) {
        const int ng = tid & 3, t4 = tid >> 2;
        const int dg = t4 & 7, eg = t4 >> 3;
        const int e0 = eg * 4, d0 = dg * 8;
        float acc[4][8];
        #pragma unroll
        for (int i = 0; i < 4; ++i)
            #pragma unroll
            for (int j = 0; j < 8; ++j) acc[i][j] = 0.f;
        #pragma unroll 5
        for (int n = ng * 25; n < ng * 25 + 25; ++n) {
            const float4 p  = ld4(&sh_S[n * SP + e0]);
            const float4 h0 = ld4(&sh_h[n * PAD + d0]);
            const float4 h1 = ld4(&sh_h[n * PAD + d0 + 4]);
            const float pv[4] = {p.x, p.y, p.z, p.w};
            const float hv[8] = {h0.x, h0.y, h0.z, h0.w, h1.x, h1.y, h1.z, h1.w};
            #pragma unroll
            for (int i = 0; i < 4; ++i)
                #pragma unroll
                for (int j = 0; j < 8; ++j) acc[i][j] += pv[i] * hv[j];
        }
        #pragma unroll
        for (int i = 0; i < 4; ++i)
            #pragma unroll
            for (int j = 0; j < 8; ++j) {
                float v = acc[i][j];
                v += __shfl_xor(v, 1);
                v += __shfl_xor(v, 2);
                acc[i][j] = v;
            }
        if (ng == 0) {
            #pragma unroll
            for (int i = 0; i < 4; ++i)
                if (e0 + i < EH) {
                    const float inv = sh_inv[e0 + i];
                    float* dst = &edge[(b * E_ + e_base + e0 + i) * D_ + d0];
                    st4(dst,     make_float4(acc[i][0]*inv, acc[i][1]*inv, acc[i][2]*inv, acc[i][3]*inv));
                    st4(dst + 4, make_float4(acc[i][4]*inv, acc[i][5]*inv, acc[i][6]*inv, acc[i][7]*inv));
                }
        }
    }
}

// ---------------------------------------------------------------------------
// edge -> node. grid (4, B), 256 threads, ~48KB LDS.
//   ht[n,d] = h[n,d] + s_c[d]   (n in this block's quarter)
//   S[e,n]  = select_k( sum_d ed[e,d]*ht[n,d]*a_k[d] ), leaky, NEG
//   P = softmax_e(S);  r[n,d] = sum_e P[e,n] ed[e,d];  h_next = r; out (+)= r
// ---------------------------------------------------------------------------
template <bool WRITE_NEXT, bool ACC>
__global__ __launch_bounds__(256, 4) void k_e2n(
    const float* __restrict__ h,    // (B,N,D)
    const float* __restrict__ s_c,  // (B,1,D)
    const float* __restrict__ Hm,   // (B,N,E)
    const float* __restrict__ a0,
    const float* __restrict__ a1,
    const float* __restrict__ a2,
    const float* __restrict__ edge, // (B,E,D)
    float* __restrict__ h_next,
    float* __restrict__ out)
{
    __shared__ float sh_ed[E_ * PAD];          // 27.2 KB
    __shared__ float sh_ht[EH * PAD];          //  6.8 KB
    __shared__ float sh_S[E_ * SP];            // 11.2 KB
    __shared__ unsigned char sh_k[E_ * KP];    //  2.8 KB  [e][ln]
    __shared__ float sh_a[3 * PAD];            //  0.8 KB
    __shared__ float sh_inv[EH];

    const int b = blockIdx.y;
    const int n_base = blockIdx.x * EH;
    const int tid = threadIdx.x;

    // ---- A: stage ----
    for (int i4 = tid; i4 < E_ * D_ / 4; i4 += 256) {
        const float4 v = ld4(&edge[b * E_ * D_ + i4 * 4]);
        st4(&sh_ed[(i4 >> 4) * PAD + (i4 & 15) * 4], v);
    }
    for (int i4 = tid; i4 < EH * D_ / 4; i4 += 256) {
        const int ln = i4 >> 4, dq = (i4 & 15) * 4;
        const float4 hv = ld4(&h[(b * N_ + n_base + ln) * D_ + dq]);
        const float4 sc = ld4(&s_c[b * D_ + dq]);
        st4(&sh_ht[ln * PAD + dq], make_float4(hv.x + sc.x, hv.y + sc.y, hv.z + sc.z, hv.w + sc.w));
    }
    if (tid < 192) {
        const int k = tid >> 6, d = tid & 63;
        sh_a[k * PAD + d] = (k == 0 ? a0 : k == 1 ? a1 : a2)[d];
    }
    for (int i = tid; i < EH * E_; i += 256) {
        const int ln = i / E_, e = i % E_;
        sh_k[e * KP + ln] = (unsigned char)(int)Hm[(b * N_ + n_base + ln) * E_ + e];
    }
    __syncthreads();

    // ---- C: scores S[e,ln]; rows {eg+25i} x 5 cols, d halves; 250 thr ----
    if (tid < 250) {
        const int t2 = tid >> 1, dh = tid & 1;
        const int cg = t2 / 25, eg = t2 % 25;       // cg 0..4
        const int ln0 = cg * 5;
        float acc[3][4][5];
        #pragma unroll
        for (int k = 0; k < 3; ++k)
            #pragma unroll
            for (int i = 0; i < 4; ++i)
                #pragma unroll
                for (int j = 0; j < 5; ++j) acc[k][i][j] = 0.f;
        const int dbase = dh * 32;
        #pragma unroll 2
        for (int s = 0; s < 8; ++s) {
            const int d0 = dbase + s * 4;
            float4 ev[4], av[3];
            #pragma unroll
            for (int i = 0; i < 4; ++i) ev[i] = ld4(&sh_ed[(eg + 25 * i) * PAD + d0]);
            #pragma unroll
            for (int k = 0; k < 3; ++k) av[k] = ld4(&sh_a[k * PAD + d0]);
            #pragma unroll
            for (int j = 0; j < 5; ++j) {
                const float4 tv = ld4(&sh_ht[(ln0 + j) * PAD + d0]);
                #pragma unroll
                for (int k = 0; k < 3; ++k) {
                    const float4 w = make_float4(tv.x * av[k].x, tv.y * av[k].y,
                                                 tv.z * av[k].z, tv.w * av[k].w);
                    #pragma unroll
                    for (int i = 0; i < 4; ++i) acc[k][i][j] += dot4(ev[i], w);
                }
            }
        }
        #pragma unroll
        for (int k = 0; k < 3; ++k)
            #pragma unroll
            for (int i = 0; i < 4; ++i)
                #pragma unroll
                for (int j = 0; j < 5; ++j)
                    acc[k][i][j] += __shfl_xor(acc[k][i][j], 1);
        #define EPI_E2N(I) { \
            _Pragma("unroll") \
            for (int j = 0; j < 5; ++j) { \
                const int kk = sh_k[(eg + 25 * (I)) * KP + ln0 + j]; \
                const float v = (kk == 1) ? acc[0][I][j] : (kk == 2) ? acc[1][I][j] : acc[2][I][j]; \
                const float lv = (v >= 0.f) ? v : LALPHA * v; \
                sh_S[(eg + 25 * (I)) * SP + ln0 + j] = kk ? lv : NEGV; } }
        if (dh == 0) { EPI_E2N(0); EPI_E2N(1); } else { EPI_E2N(2); EPI_E2N(3); }
        #undef EPI_E2N
    }
    __syncthreads();

    // ---- D: softmax over e per ln-column; 200 thr ----
    if (tid < 200) {
        const int ln = tid >> 3, g = tid & 7;
        float mx = -INFINITY;
        for (int e = g; e < E_; e += 8) mx = fmaxf(mx, sh_S[e * SP + ln]);
        mx = fmaxf(mx, __shfl_xor(mx, 1));
        mx = fmaxf(mx, __shfl_xor(mx, 2));
        mx = fmaxf(mx, __shfl_xor(mx, 4));
        float sum = 0.f;
        for (int e = g; e < E_; e += 8) {
            const float p = __expf(sh_S[e * SP + ln] - mx);
            sh_S[e * SP + ln] = p;
            sum += p;
        }
        sum += __shfl_xor(sum, 1);
        sum += __shfl_xor(sum, 2);
        sum += __shfl_xor(sum, 4);
        if (g == 0) sh_inv[ln] = 1.f / sum;
    }
    __syncthreads();

    // ---- R: r[ln,d] = inv[ln]*sum_e P[e,ln] ed[e,d]; tile (4ln,8d), e-split-4; 224 thr ----
    if (tid < 224) {
        const int es = tid & 3, t4 = tid >> 2;
        const int dg = t4 & 7, lg = t4 >> 3;        // lg 0..6
        const int ln0 = lg * 4, d0 = dg * 8;
        float acc[4][8];
        #pragma unroll
        for (int i = 0; i < 4; ++i)
            #pragma unroll
            for (int j = 0; j < 8; ++j) acc[i][j] = 0.f;
        #pragma unroll 5
        for (int e = es * 25; e < es * 25 + 25; ++e) {
            const float4 p   = ld4(&sh_S[e * SP + ln0]);
            const float4 e0v = ld4(&sh_ed[e * PAD + d0]);
            const float4 e1v = ld4(&sh_ed[e * PAD + d0 + 4]);
            const float pv[4] = {p.x, p.y, p.z, p.w};
            const float ev[8] = {e0v.x, e0v.y, e0v.z, e0v.w, e1v.x, e1v.y, e1v.z, e1v.w};
            #pragma unroll
            for (int i = 0; i < 4; ++i)
                #pragma unroll
                for (int j = 0; j < 8; ++j) acc[i][j] += pv[i] * ev[j];
        }
        #pragma unroll
        for (int i = 0; i < 4; ++i)
            #pragma unroll
            for (int j = 0; j < 8; ++j) {
                float v = acc[i][j];
                v += __shfl_xor(v, 1);
                v += __shfl_xor(v, 2);
                acc[i][j] = v;
            }
        if (es == 0) {
            #pragma unroll
            for (int i = 0; i < 4; ++i)
                if (ln0 + i < EH) {
                    const float inv = sh_inv[ln0 + i];
                    float r[8];
                    #pragma unroll
                    for (int j = 0; j < 8; ++j) r[j] = acc[i][j] * inv;
                    const int idx = (b * N_ + n_base + ln0 + i) * D_ + d0;
                    if (WRITE_NEXT) {
                        st4(&h_next[idx],     make_float4(r[0], r[1], r[2], r[3]));
                        st4(&h_next[idx + 4], make_float4(r[4], r[5], r[6], r[7]));
                    }
                    if (ACC) {
                        const float4 o0 = ld4(&out[idx]);
                        const float4 o1 = ld4(&out[idx + 4]);
                        st4(&out[idx],     make_float4(o0.x + r[0], o0.y + r[1], o0.z + r[2], o0.w + r[3]));
                        st4(&out[idx + 4], make_float4(o1.x + r[4], o1.y + r[5], o1.z + r[6], o1.w + r[7]));
                    } else {
                        st4(&out[idx],     make_float4(r[0], r[1], r[2], r[3]));
                        st4(&out[idx + 4], make_float4(r[4], r[5], r[6], r[7]));
                    }
                }
        }
    }
}

extern "C" void kernel_launch(void* const* d_in, const int* in_sizes, int n_in,
                              void* d_out, int out_size, void* d_ws, size_t ws_size,
                              hipStream_t stream) {
    const float* hidden = (const float*)d_in[0];
    const float* Hm     = (const float*)d_in[1];
    const float* s_c    = (const float*)d_in[2];
    const float* a10    = (const float*)d_in[3];
    const float* a11    = (const float*)d_in[4];
    const float* a12    = (const float*)d_in[5];
    const float* a20    = (const float*)d_in[6];
    const float* a21    = (const float*)d_in[7];
    const float* a22    = (const float*)d_in[8];
    float* out = (float*)d_out;

    float* edge  = (float*)d_ws;                 // B*E*D
    float* hnext = edge + (size_t)B_ * E_ * D_;  // B*N*D

    const dim3 grid(4, B_);

    // layer 1
    k_n2e<<<grid, 256, 0, stream>>>(hidden, Hm, a10, a11, a12, edge);
    k_e2n<true, false><<<grid, 256, 0, stream>>>(hidden, s_c, Hm, a20, a21, a22, edge, hnext, out);
    // layer 2
    k_n2e<<<grid, 256, 0, stream>>>(hnext, Hm, a10, a11, a12, edge);
    k_e2n<false, true><<<grid, 256, 0, stream>>>(hnext, s_c, Hm, a20, a21, a22, edge, nullptr, out);
}

// Round 6
// 136.751 us; speedup vs baseline: 1.3818x; 1.3818x over previous
//
#include <hip/hip_runtime.h>
#include <math.h>

#define B_ 128
#define N_ 100
#define E_ 100
#define D_ 64
#define EH 50
#define LALPHA 0.2f
#define NEGV -9e15f

typedef __attribute__((ext_vector_type(8))) short short8;
typedef __attribute__((ext_vector_type(4))) short short4v;
typedef __attribute__((ext_vector_type(4))) float f32x4;

__device__ __forceinline__ float4 ld4(const float* p) { return *reinterpret_cast<const float4*>(p); }

__device__ __forceinline__ unsigned short f2bf(float x) {
    union { float f; unsigned u; } c; c.f = x;
    return (unsigned short)((c.u + 0x7FFF + ((c.u >> 16) & 1)) >> 16);
}
__device__ __forceinline__ short8 pk8(const unsigned short h[8]) {
    short8 r = { (short)h[0], (short)h[1], (short)h[2], (short)h[3],
                 (short)h[4], (short)h[5], (short)h[6], (short)h[7] };
    return r;
}

#define MFMA(a, b, c) __builtin_amdgcn_mfma_f32_16x16x32_bf16((a), (b), (c), 0, 0, 0)

// ---------------------------------------------------------------------------
// node -> edge. grid (2,B), 512 thr. LDS ~137KB, 1 block/CU.
// ec = m01^T.h (MFMA) ; w_k = ec*a_k (hi/lo) ; S[e][n] = w_k . h^T (MFMA 2-term)
// P = softmax_n ; edge = P^T.h (MFMA)
// ---------------------------------------------------------------------------
__global__ __launch_bounds__(512, 1) void k_n2e(
    const float* __restrict__ h, const float* __restrict__ Hm,
    const float* __restrict__ a0, const float* __restrict__ a1,
    const float* __restrict__ a2, float* __restrict__ edge)
{
    __shared__ unsigned short hh[128 * 72];     // h bf16 [n][d]
    __shared__ unsigned short hT[64 * 136];     // h bf16 [d][n], n-pad zero
    __shared__ unsigned short m01[64 * 136];    // mask bf16 [e][n], zero-padded
    __shared__ float Sbuf[100 * 64];            // scores [n][e]; doubles as ec f32 [64][68]
    __shared__ unsigned short wh[3 * 64 * 72];  // w hi [k][e][d]; first 8704 reused as PT [e][n]
    __shared__ unsigned short wl[3 * 64 * 72];  // w lo
    __shared__ unsigned char kk[100 * 64];
    __shared__ float sinv[64];

    const int b = blockIdx.y, e_base = blockIdx.x * EH;
    const int tid = threadIdx.x;
    const int wv = tid >> 6, ln = tid & 63, l15 = ln & 15, l4 = ln >> 4;

    // ---- A0: zero m01, zero hT n-pad, stage h (hi bf16 + transposed copy) ----
    for (int i = tid; i < 1088; i += 512) {
        short8 z = { 0,0,0,0,0,0,0,0 };
        reinterpret_cast<short8*>(m01)[i] = z;
    }
    for (int i = tid; i < 64 * 36; i += 512) { int d = i / 36, n = 100 + i % 36; hT[d * 136 + n] = 0; }
    for (int g = tid; g < 1600; g += 512) {
        const int n = g >> 4, d0 = (g & 15) * 4;
        const float4 v = ld4(&h[(b * N_ + n) * D_ + d0]);
        unsigned short q[4] = { f2bf(v.x), f2bf(v.y), f2bf(v.z), f2bf(v.w) };
        short4v p = { (short)q[0], (short)q[1], (short)q[2], (short)q[3] };
        *reinterpret_cast<short4v*>(&hh[n * 72 + d0]) = p;
        hT[(d0 + 0) * 136 + n] = q[0]; hT[(d0 + 1) * 136 + n] = q[1];
        hT[(d0 + 2) * 136 + n] = q[2]; hT[(d0 + 3) * 136 + n] = q[3];
    }
    __syncthreads();
    // ---- A1: masks ----
    for (int i = tid; i < 6400; i += 512) {
        const int n = i >> 6, e = i & 63;
        if (e < EH) {
            const int v = (int)Hm[(b * N_ + n) * E_ + e_base + e];
            kk[n * 64 + e] = (unsigned char)v;
            m01[e * 136 + n] = (v > 0) ? (unsigned short)0x3F80 : (unsigned short)0;
        } else kk[n * 64 + e] = 0;
    }
    __syncthreads();

    // ---- B: ec[e][d] via MFMA. M=e(4t), N=d(4t), K=n(4 steps). wave: 1Mx2N ----
    {
        const int Mt = wv >> 1, NtB = (wv & 1) * 2;
        f32x4 acc0 = { 0,0,0,0 }, acc1 = { 0,0,0,0 };
        #pragma unroll
        for (int ks = 0; ks < 4; ++ks) {
            const int ko = ks * 32 + l4 * 8;
            short8 af = *reinterpret_cast<const short8*>(&m01[(Mt * 16 + l15) * 136 + ko]);
            short8 b0 = *reinterpret_cast<const short8*>(&hT[((NtB + 0) * 16 + l15) * 136 + ko]);
            short8 b1 = *reinterpret_cast<const short8*>(&hT[((NtB + 1) * 16 + l15) * 136 + ko]);
            acc0 = MFMA(af, b0, acc0);
            acc1 = MFMA(af, b1, acc1);
        }
        float* ec = Sbuf;
        #pragma unroll
        for (int r = 0; r < 4; ++r) {
            const int e = Mt * 16 + l4 * 4 + r;
            ec[e * 68 + NtB * 16 + l15] = acc0[r];
            ec[e * 68 + (NtB + 1) * 16 + l15] = acc1[r];
        }
    }
    __syncthreads();

    // ---- B2: w_k = ec * a_k -> bf16 hi/lo ----
    for (int g = tid; g < 1536; g += 512) {
        const int k = g >> 9, rem = g & 511, e = rem >> 3, d0 = (rem & 7) * 8;
        const float* ec = Sbuf;
        const float* ap = (k == 0) ? a0 : (k == 1) ? a1 : a2;
        const float4 e0 = ld4(&ec[e * 68 + d0]), e1 = ld4(&ec[e * 68 + d0 + 4]);
        const float4 av0 = ld4(&ap[d0]), av1 = ld4(&ap[d0 + 4]);
        const float wv8[8] = { e0.x * av0.x, e0.y * av0.y, e0.z * av0.z, e0.w * av0.w,
                               e1.x * av1.x, e1.y * av1.y, e1.z * av1.z, e1.w * av1.w };
        unsigned short hi[8], lo[8];
        #pragma unroll
        for (int j = 0; j < 8; ++j) {
            hi[j] = f2bf(wv8[j]);
            union { unsigned u; float f; } c; c.u = (unsigned)hi[j] << 16;
            lo[j] = f2bf(wv8[j] - c.f);
        }
        *reinterpret_cast<short8*>(&wh[(k * 64 + e) * 72 + d0]) = pk8(hi);
        *reinterpret_cast<short8*>(&wl[(k * 64 + e) * 72 + d0]) = pk8(lo);
    }
    __syncthreads();

    // ---- C: S[e][n] MFMA. M=e(4t), N=n(8t), K=d(2). wave: 1Mx4N, 3k, 2-term ----
    {
        const int Mt = wv >> 1, NtB = (wv & 1) * 4;
        f32x4 acc[3][4];
        #pragma unroll
        for (int k = 0; k < 3; ++k)
            #pragma unroll
            for (int j = 0; j < 4; ++j) { f32x4 z = { 0,0,0,0 }; acc[k][j] = z; }
        #pragma unroll
        for (int ks = 0; ks < 2; ++ks) {
            const int ko = ks * 32 + l4 * 8;
            short8 bf[4];
            #pragma unroll
            for (int j = 0; j < 4; ++j)
                bf[j] = *reinterpret_cast<const short8*>(&hh[((NtB + j) * 16 + l15) * 72 + ko]);
            #pragma unroll
            for (int k = 0; k < 3; ++k) {
                short8 ah = *reinterpret_cast<const short8*>(&wh[(k * 64 + Mt * 16 + l15) * 72 + ko]);
                short8 al = *reinterpret_cast<const short8*>(&wl[(k * 64 + Mt * 16 + l15) * 72 + ko]);
                #pragma unroll
                for (int j = 0; j < 4; ++j) {
                    acc[k][j] = MFMA(ah, bf[j], acc[k][j]);
                    acc[k][j] = MFMA(al, bf[j], acc[k][j]);
                }
            }
        }
        #pragma unroll
        for (int j = 0; j < 4; ++j) {
            const int n = (NtB + j) * 16 + l15;
            if (n < N_) {
                const int e0r = Mt * 16 + l4 * 4;
                const unsigned kw = *reinterpret_cast<const unsigned*>(&kk[n * 64 + e0r]);
                f32x4 sv;
                #pragma unroll
                for (int r = 0; r < 4; ++r) {
                    const int kv = (kw >> (8 * r)) & 255;
                    float v = (kv == 1) ? acc[0][j][r] : (kv == 2) ? acc[1][j][r] : acc[2][j][r];
                    v = (v >= 0.f) ? v : LALPHA * v;
                    sv[r] = kv ? v : NEGV;
                }
                *reinterpret_cast<f32x4*>(&Sbuf[n * 64 + e0r]) = sv;
            }
        }
    }
    __syncthreads();

    // ---- D: softmax over n per e-col (400 thr); spares zero PT region ----
    if (tid < 400) {
        const int e = tid >> 3, g = tid & 7;
        float mx = -INFINITY;
        for (int n = g; n < N_; n += 8) mx = fmaxf(mx, Sbuf[n * 64 + e]);
        mx = fmaxf(mx, __shfl_xor(mx, 1)); mx = fmaxf(mx, __shfl_xor(mx, 2)); mx = fmaxf(mx, __shfl_xor(mx, 4));
        float sum = 0.f;
        for (int n = g; n < N_; n += 8) { const float p = __expf(Sbuf[n * 64 + e] - mx); Sbuf[n * 64 + e] = p; sum += p; }
        sum += __shfl_xor(sum, 1); sum += __shfl_xor(sum, 2); sum += __shfl_xor(sum, 4);
        if (g == 0) sinv[e] = 1.f / sum;
    } else {
        for (int i = tid - 400; i < 1088; i += 112) {
            short8 z = { 0,0,0,0,0,0,0,0 };
            reinterpret_cast<short8*>(wh)[i] = z;
        }
    }
    __syncthreads();

    // ---- D2: PT[e][n] = bf16(P) ----
    {
        unsigned short* PT = wh;
        for (int i = tid; i < 6400; i += 512) {
            const int n = i >> 6, e = i & 63;
            if (e < EH) PT[e * 136 + n] = f2bf(Sbuf[n * 64 + e] * sinv[e]);
        }
    }
    __syncthreads();

    // ---- E: edge[e][d] = PT . hT. M=e(4t), N=d(4t), K=n(4). wave: 1Mx2N ----
    {
        const unsigned short* PT = wh;
        const int Mt = wv >> 1, NtB = (wv & 1) * 2;
        f32x4 acc0 = { 0,0,0,0 }, acc1 = { 0,0,0,0 };
        #pragma unroll
        for (int ks = 0; ks < 4; ++ks) {
            const int ko = ks * 32 + l4 * 8;
            short8 af = *reinterpret_cast<const short8*>(&PT[(Mt * 16 + l15) * 136 + ko]);
            short8 b0 = *reinterpret_cast<const short8*>(&hT[((NtB + 0) * 16 + l15) * 136 + ko]);
            short8 b1 = *reinterpret_cast<const short8*>(&hT[((NtB + 1) * 16 + l15) * 136 + ko]);
            acc0 = MFMA(af, b0, acc0);
            acc1 = MFMA(af, b1, acc1);
        }
        #pragma unroll
        for (int r = 0; r < 4; ++r) {
            const int e = Mt * 16 + l4 * 4 + r;
            if (e < EH) {
                edge[(b * E_ + e_base + e) * D_ + NtB * 16 + l15] = acc0[r];
                edge[(b * E_ + e_base + e) * D_ + (NtB + 1) * 16 + l15] = acc1[r];
            }
        }
    }
}

// ---------------------------------------------------------------------------
// edge -> node. grid (2,B), 512 thr. LDS ~123KB.
// wt_k = (h+s_c)*a_k (hi/lo) ; S2[e][n'] = wt_k . edge^T ; P2 = softmax_e
// out = P2^T.edge
// ---------------------------------------------------------------------------
template <bool WRITE_NEXT, bool ACC>
__global__ __launch_bounds__(512, 1) void k_e2n(
    const float* __restrict__ h, const float* __restrict__ s_c,
    const float* __restrict__ Hm, const float* __restrict__ a0,
    const float* __restrict__ a1, const float* __restrict__ a2,
    const float* __restrict__ edge, float* __restrict__ h_next,
    float* __restrict__ out)
{
    __shared__ unsigned short eh[128 * 72];     // edge bf16 [e][d]
    __shared__ unsigned short ehT[64 * 136];    // edge bf16 [d][e], e-pad zero
    __shared__ unsigned short wth[3 * 64 * 72]; // wt hi [k][n'][d]; first 8704 reused as P2T [n'][e]
    __shared__ unsigned short wtl[3 * 64 * 72];
    __shared__ float S2[100 * 64];              // scores [e][n']
    __shared__ unsigned char kk2[100 * 64];     // [e][n']
    __shared__ float sinv2[64];

    const int b = blockIdx.y, n_base = blockIdx.x * EH;
    const int tid = threadIdx.x;
    const int wv = tid >> 6, ln = tid & 63, l15 = ln & 15, l4 = ln >> 4;

    // ---- A: zero ehT e-pad; stage edge; build wt; masks ----
    for (int i = tid; i < 64 * 36; i += 512) { int d = i / 36, e = 100 + i % 36; ehT[d * 136 + e] = 0; }
    for (int g = tid; g < 1600; g += 512) {
        const int e = g >> 4, d0 = (g & 15) * 4;
        const float4 v = ld4(&edge[(b * E_ + e) * D_ + d0]);
        unsigned short q[4] = { f2bf(v.x), f2bf(v.y), f2bf(v.z), f2bf(v.w) };
        short4v p = { (short)q[0], (short)q[1], (short)q[2], (short)q[3] };
        *reinterpret_cast<short4v*>(&eh[e * 72 + d0]) = p;
        ehT[(d0 + 0) * 136 + e] = q[0]; ehT[(d0 + 1) * 136 + e] = q[1];
        ehT[(d0 + 2) * 136 + e] = q[2]; ehT[(d0 + 3) * 136 + e] = q[3];
    }
    for (int g = tid; g < 1536; g += 512) {
        const int k = g >> 9, rem = g & 511, np = rem >> 3, d0 = (rem & 7) * 8;
        if (np < EH) {
            const float* ap = (k == 0) ? a0 : (k == 1) ? a1 : a2;
            const float4 hv0 = ld4(&h[(b * N_ + n_base + np) * D_ + d0]);
            const float4 hv1 = ld4(&h[(b * N_ + n_base + np) * D_ + d0 + 4]);
            const float4 sc0 = ld4(&s_c[b * D_ + d0]), sc1 = ld4(&s_c[b * D_ + d0 + 4]);
            const float4 av0 = ld4(&ap[d0]), av1 = ld4(&ap[d0 + 4]);
            const float wv8[8] = { (hv0.x + sc0.x) * av0.x, (hv0.y + sc0.y) * av0.y,
                                   (hv0.z + sc0.z) * av0.z, (hv0.w + sc0.w) * av0.w,
                                   (hv1.x + sc1.x) * av1.x, (hv1.y + sc1.y) * av1.y,
                                   (hv1.z + sc1.z) * av1.z, (hv1.w + sc1.w) * av1.w };
            unsigned short hi[8], lo[8];
            #pragma unroll
            for (int j = 0; j < 8; ++j) {
                hi[j] = f2bf(wv8[j]);
                union { unsigned u; float f; } c; c.u = (unsigned)hi[j] << 16;
                lo[j] = f2bf(wv8[j] - c.f);
            }
            *reinterpret_cast<short8*>(&wth[(k * 64 + np) * 72 + d0]) = pk8(hi);
            *reinterpret_cast<short8*>(&wtl[(k * 64 + np) * 72 + d0]) = pk8(lo);
        }
    }
    for (int i = tid; i < 6400; i += 512) {
        const int e = i >> 6, np = i & 63;
        if (np < EH) kk2[e * 64 + np] = (unsigned char)(int)Hm[(b * N_ + n_base + np) * E_ + e];
        else kk2[e * 64 + np] = 0;
    }
    __syncthreads();

    // ---- C2: S2[e][n']? compute C[n'][e]: M=n'(4t), N=e(8t), K=d(2) ----
    {
        const int Mt = wv >> 1, NtB = (wv & 1) * 4;
        f32x4 acc[3][4];
        #pragma unroll
        for (int k = 0; k < 3; ++k)
            #pragma unroll
            for (int j = 0; j < 4; ++j) { f32x4 z = { 0,0,0,0 }; acc[k][j] = z; }
        #pragma unroll
        for (int ks = 0; ks < 2; ++ks) {
            const int ko = ks * 32 + l4 * 8;
            short8 bf[4];
            #pragma unroll
            for (int j = 0; j < 4; ++j)
                bf[j] = *reinterpret_cast<const short8*>(&eh[((NtB + j) * 16 + l15) * 72 + ko]);
            #pragma unroll
            for (int k = 0; k < 3; ++k) {
                short8 ah = *reinterpret_cast<const short8*>(&wth[(k * 64 + Mt * 16 + l15) * 72 + ko]);
                short8 al = *reinterpret_cast<const short8*>(&wtl[(k * 64 + Mt * 16 + l15) * 72 + ko]);
                #pragma unroll
                for (int j = 0; j < 4; ++j) {
                    acc[k][j] = MFMA(ah, bf[j], acc[k][j]);
                    acc[k][j] = MFMA(al, bf[j], acc[k][j]);
                }
            }
        }
        #pragma unroll
        for (int j = 0; j < 4; ++j) {
            const int e = (NtB + j) * 16 + l15;
            if (e < E_) {
                const int np0 = Mt * 16 + l4 * 4;
                const unsigned kw = *reinterpret_cast<const unsigned*>(&kk2[e * 64 + np0]);
                f32x4 sv;
                #pragma unroll
                for (int r = 0; r < 4; ++r) {
                    const int kv = (kw >> (8 * r)) & 255;
                    float v = (kv == 1) ? acc[0][j][r] : (kv == 2) ? acc[1][j][r] : acc[2][j][r];
                    v = (v >= 0.f) ? v : LALPHA * v;
                    sv[r] = kv ? v : NEGV;
                }
                *reinterpret_cast<f32x4*>(&S2[e * 64 + np0]) = sv;
            }
        }
    }
    __syncthreads();

    // ---- D: softmax over e per n'-col; spares zero P2T ----
    if (tid < 400) {
        const int np = tid >> 3, g = tid & 7;
        float mx = -INFINITY;
        for (int e = g; e < E_; e += 8) mx = fmaxf(mx, S2[e * 64 + np]);
        mx = fmaxf(mx, __shfl_xor(mx, 1)); mx = fmaxf(mx, __shfl_xor(mx, 2)); mx = fmaxf(mx, __shfl_xor(mx, 4));
        float sum = 0.f;
        for (int e = g; e < E_; e += 8) { const float p = __expf(S2[e * 64 + np] - mx); S2[e * 64 + np] = p; sum += p; }
        sum += __shfl_xor(sum, 1); sum += __shfl_xor(sum, 2); sum += __shfl_xor(sum, 4);
        if (g == 0) sinv2[np] = 1.f / sum;
    } else {
        for (int i = tid - 400; i < 1088; i += 112) {
            short8 z = { 0,0,0,0,0,0,0,0 };
            reinterpret_cast<short8*>(wth)[i] = z;
        }
    }
    __syncthreads();

    // ---- D2: P2T[n'][e] ----
    {
        unsigned short* P2T = wth;
        for (int i = tid; i < 6400; i += 512) {
            const int e = i >> 6, np = i & 63;
            if (np < EH) P2T[np * 136 + e] = f2bf(S2[e * 64 + np] * sinv2[np]);
        }
    }
    __syncthreads();

    // ---- Out: r[n'][d] = P2T . ehT. M=n'(4t), N=d(4t), K=e(4) ----
    {
        const unsigned short* P2T = wth;
        const int Mt = wv >> 1, NtB = (wv & 1) * 2;
        f32x4 acc0 = { 0,0,0,0 }, acc1 = { 0,0,0,0 };
        #pragma unroll
        for (int ks = 0; ks < 4; ++ks) {
            const int ko = ks * 32 + l4 * 8;
            short8 af = *reinterpret_cast<const short8*>(&P2T[(Mt * 16 + l15) * 136 + ko]);
            short8 b0 = *reinterpret_cast<const short8*>(&ehT[((NtB + 0) * 16 + l15) * 136 + ko]);
            short8 b1 = *reinterpret_cast<const short8*>(&ehT[((NtB + 1) * 16 + l15) * 136 + ko]);
            acc0 = MFMA(af, b0, acc0);
            acc1 = MFMA(af, b1, acc1);
        }
        #pragma unroll
        for (int r = 0; r < 4; ++r) {
            const int np = Mt * 16 + l4 * 4 + r;
            if (np < EH) {
                const int idx = (b * N_ + n_base + np) * D_ + NtB * 16 + l15;
                const float v0 = acc0[r], v1 = acc1[r];
                if (WRITE_NEXT) { h_next[idx] = v0; h_next[idx + 16] = v1; }
                if (ACC) { out[idx] += v0; out[idx + 16] += v1; }
                else     { out[idx] = v0;  out[idx + 16] = v1; }
            }
        }
    }
}

extern "C" void kernel_launch(void* const* d_in, const int* in_sizes, int n_in,
                              void* d_out, int out_size, void* d_ws, size_t ws_size,
                              hipStream_t stream) {
    const float* hidden = (const float*)d_in[0];
    const float* Hm     = (const float*)d_in[1];
    const float* s_c    = (const float*)d_in[2];
    const float* a10    = (const float*)d_in[3];
    const float* a11    = (const float*)d_in[4];
    const float* a12    = (const float*)d_in[5];
    const float* a20    = (const float*)d_in[6];
    const float* a21    = (const float*)d_in[7];
    const float* a22    = (const float*)d_in[8];
    float* out = (float*)d_out;

    float* edge  = (float*)d_ws;
    float* hnext = edge + (size_t)B_ * E_ * D_;

    const dim3 grid(2, B_);

    k_n2e<<<grid, 512, 0, stream>>>(hidden, Hm, a10, a11, a12, edge);
    k_e2n<true, false><<<grid, 512, 0, stream>>>(hidden, s_c, Hm, a20, a21, a22, edge, hnext, out);
    k_n2e<<<grid, 512, 0, stream>>>(hnext, Hm, a10, a11, a12, edge);
    k_e2n<false, true><<<grid, 512, 0, stream>>>(hnext, s_c, Hm, a20, a21, a22, edge, nullptr, out);
}

// Round 7
// 134.587 us; speedup vs baseline: 1.4040x; 1.0161x over previous
//
#include <hip/hip_runtime.h>
#include <math.h>

#define B_ 128
#define N_ 100
#define E_ 100
#define D_ 64
#define EH 25
#define LALPHA 0.2f
#define NEGV -9e15f

typedef __attribute__((ext_vector_type(8))) short short8;
typedef __attribute__((ext_vector_type(4))) short short4v;
typedef __attribute__((ext_vector_type(4))) float f32x4;

__device__ __forceinline__ float4 ld4(const float* p) { return *reinterpret_cast<const float4*>(p); }

__device__ __forceinline__ unsigned short f2bf(float x) {
    union { float f; unsigned u; } c; c.f = x;
    return (unsigned short)((c.u + 0x7FFF + ((c.u >> 16) & 1)) >> 16);
}
__device__ __forceinline__ float bf2f(unsigned short h) {
    union { unsigned u; float f; } c; c.u = (unsigned)h << 16;
    return c.f;
}

#define MFMA(a, b, c) __builtin_amdgcn_mfma_f32_16x16x32_bf16((a), (b), (c), 0, 0, 0)

// ---------------------------------------------------------------------------
// node -> edge. grid (4,B), 512 thr, LDS ~57.6KB -> 2 blocks/CU (16 waves).
//   ec[e,d]  = sum_n m01[e,n] h[n,d]               (MFMA, e-quarter)
//   S[e][n]  = select_k( sum_d (ec*a_k)[e,d] h[n,d] ), leaky, NEG  (MFMA, reg-built A)
//   row softmax over n; PT[e][n] bf16; edge = PT.hT (MFMA)
// ---------------------------------------------------------------------------
__global__ __launch_bounds__(512, 4) void k_n2e(
    const float* __restrict__ h, const float* __restrict__ Hm,
    const float* __restrict__ a0, const float* __restrict__ a1,
    const float* __restrict__ a2, float* __restrict__ edge)
{
    __shared__ __align__(16) unsigned short hh[112 * 72];   // [n][d]; rows 100..111 zero. PT alias.
    __shared__ __align__(16) unsigned short hT[64 * 136];   // [d][n]; cols 100..135 zero
    __shared__ __align__(16) float S[EH * 112];             // scores [e_loc][n]; m01 alias (first 8704B)
    __shared__ __align__(16) float ec[32 * 66];             // [e_loc][d] f32
    __shared__ __align__(16) unsigned char kk[112 * 32];    // [n][e_loc]
    __shared__ __align__(16) float a_lds[3 * 68];

    unsigned short* m01 = reinterpret_cast<unsigned short*>(S);   // [32][136] hw
    unsigned short* PT  = hh;                                      // [32][136] hw

    const int b = blockIdx.y, e_base = blockIdx.x * EH;
    const int tid = threadIdx.x;
    const int wv = tid >> 6, ln = tid & 63, l15 = ln & 15, l4 = ln >> 4;

    // ---- A0: stage + zero pads (disjoint regions, no race) ----
    for (int g = tid; g < 1600; g += 512) {
        const int n = g >> 4, d0 = (g & 15) * 4;
        const float4 v = ld4(&h[(b * N_ + n) * D_ + d0]);
        unsigned short q[4] = { f2bf(v.x), f2bf(v.y), f2bf(v.z), f2bf(v.w) };
        short4v p = { (short)q[0], (short)q[1], (short)q[2], (short)q[3] };
        *reinterpret_cast<short4v*>(&hh[n * 72 + d0]) = p;
        hT[(d0 + 0) * 136 + n] = q[0]; hT[(d0 + 1) * 136 + n] = q[1];
        hT[(d0 + 2) * 136 + n] = q[2]; hT[(d0 + 3) * 136 + n] = q[3];
    }
    for (int i = tid; i < 1536; i += 512) {          // hh rows 100..111 = 0
        const int n = 100 + (i >> 7), d = i & 127;
        if (d < 72) hh[n * 72 + d] = 0;
    }
    for (int i = tid; i < 4096; i += 512) {          // hT cols 100..135 = 0
        const int d = i >> 6, c = i & 63;
        if (c < 36) hT[d * 136 + 100 + c] = 0;
    }
    for (int i = tid; i < 544; i += 512) {           // m01 = 0 (4352 hw)
        short8 z = { 0,0,0,0,0,0,0,0 };
        reinterpret_cast<short8*>(m01)[i] = z;
    }
    if (tid < 192) {
        const int k = tid >> 6, d = tid & 63;
        a_lds[k * 68 + d] = (k == 0 ? a0 : k == 1 ? a1 : a2)[d];
    }
    __syncthreads();

    // ---- A1: masks (kk + m01 fill) ----
    for (int i = tid; i < 3584; i += 512) {
        const int n = i >> 5, le = i & 31;
        int v = 0;
        if (n < 100 && le < EH) v = (int)Hm[(b * N_ + n) * E_ + e_base + le];
        kk[n * 32 + le] = (unsigned char)v;
        if (v > 0) m01[le * 136 + n] = 0x3F80;   // 1.0bf16
    }
    __syncthreads();

    // ---- B: ec = m01 . hT^T. M=e (2 tiles), N=d (4 tiles). wave=(Mt,Nt) ----
    {
        const int Mt = wv >> 2, Nt = wv & 3;
        f32x4 acc = { 0,0,0,0 };
        #pragma unroll
        for (int ks = 0; ks < 4; ++ks) {
            const int ko = ks * 32 + l4 * 8;
            short8 af = *reinterpret_cast<const short8*>(&m01[(Mt * 16 + l15) * 136 + ko]);
            short8 bf = *reinterpret_cast<const short8*>(&hT[(Nt * 16 + l15) * 136 + ko]);
            acc = MFMA(af, bf, acc);
        }
        #pragma unroll
        for (int r = 0; r < 4; ++r)
            ec[(Mt * 16 + l4 * 4 + r) * 66 + Nt * 16 + l15] = acc[r];
    }
    __syncthreads();

    // ---- C: scores S[e][n]. M=e (2 tiles), N=n (7 tiles). A built in regs ----
    {
        const int Mt = wv >> 2, NtB = (wv & 3) * 2;
        const int ntiles = (NtB == 6) ? 1 : 2;
        f32x4 acc[3][2];
        #pragma unroll
        for (int k = 0; k < 3; ++k)
            #pragma unroll
            for (int j = 0; j < 2; ++j) { f32x4 z = { 0,0,0,0 }; acc[k][j] = z; }
        const int arow = Mt * 16 + l15;
        #pragma unroll
        for (int ks = 0; ks < 2; ++ks) {
            const int ko = ks * 32 + l4 * 8;
            short8 bf[2];
            #pragma unroll
            for (int j = 0; j < 2; ++j)
                if (j < ntiles)
                    bf[j] = *reinterpret_cast<const short8*>(&hh[((NtB + j) * 16 + l15) * 72 + ko]);
            float ev[8];
            #pragma unroll
            for (int jj = 0; jj < 8; ++jj) ev[jj] = ec[arow * 66 + ko + jj];
            #pragma unroll
            for (int k = 0; k < 3; ++k) {
                short8 ah, al;
                #pragma unroll
                for (int jj = 0; jj < 8; ++jj) {
                    const float w = ev[jj] * a_lds[k * 68 + ko + jj];
                    const unsigned short hi = f2bf(w);
                    ah[jj] = (short)hi;
                    al[jj] = (short)f2bf(w - bf2f(hi));
                }
                #pragma unroll
                for (int j = 0; j < 2; ++j)
                    if (j < ntiles) {
                        acc[k][j] = MFMA(ah, bf[j], acc[k][j]);
                        acc[k][j] = MFMA(al, bf[j], acc[k][j]);
                    }
            }
        }
        #pragma unroll
        for (int j = 0; j < 2; ++j)
            if (j < ntiles) {
                const int n = (NtB + j) * 16 + l15;
                const int e0 = Mt * 16 + l4 * 4;
                const unsigned kw = *reinterpret_cast<const unsigned*>(&kk[n * 32 + e0]);
                #pragma unroll
                for (int r = 0; r < 4; ++r) {
                    const int er = e0 + r;
                    if (er < EH) {
                        const int kv = (kw >> (8 * r)) & 255;
                        float v = (kv == 1) ? acc[0][j][r] : (kv == 2) ? acc[1][j][r] : acc[2][j][r];
                        v = (v >= 0.f) ? v : LALPHA * v;
                        S[er * 112 + n] = kv ? v : NEGV;
                    }
                }
            }
    }
    __syncthreads();

    // ---- D: row softmax over n + PT quantize (per wave, rows e=wv+8t) ----
    {
        const int n1 = ln, n2 = ln + 64;
        #pragma unroll
        for (int t = 0; t < 4; ++t) {
            const int e = wv + 8 * t;
            if (e < EH) {
                const float s1 = S[e * 112 + n1];
                const float s2 = (n2 < 100) ? S[e * 112 + n2] : -INFINITY;
                float mx = fmaxf(s1, s2);
                #pragma unroll
                for (int off = 32; off; off >>= 1) mx = fmaxf(mx, __shfl_xor(mx, off));
                const float p1 = __expf(s1 - mx);
                const float p2 = (n2 < 100) ? __expf(s2 - mx) : 0.f;
                float sum = p1 + p2;
                #pragma unroll
                for (int off = 32; off; off >>= 1) sum += __shfl_xor(sum, off);
                const float inv = 1.f / sum;
                PT[e * 136 + n1] = f2bf(p1 * inv);
                PT[e * 136 + n2] = (n2 < 100) ? f2bf(p2 * inv) : (unsigned short)0;
            }
        }
    }
    __syncthreads();

    // ---- E: edge = PT . hT. M=e (2 tiles), N=d (4 tiles) ----
    {
        const int Mt = wv >> 2, Nt = wv & 3;
        f32x4 acc = { 0,0,0,0 };
        #pragma unroll
        for (int ks = 0; ks < 4; ++ks) {
            const int ko = ks * 32 + l4 * 8;
            short8 af = *reinterpret_cast<const short8*>(&PT[(Mt * 16 + l15) * 136 + ko]);
            short8 bf = *reinterpret_cast<const short8*>(&hT[(Nt * 16 + l15) * 136 + ko]);
            acc = MFMA(af, bf, acc);
        }
        #pragma unroll
        for (int r = 0; r < 4; ++r) {
            const int e = Mt * 16 + l4 * 4 + r;
            if (e < EH)
                edge[(b * E_ + e_base + e) * D_ + Nt * 16 + l15] = acc[r];
        }
    }
}

// ---------------------------------------------------------------------------
// edge -> node. grid (4,B), 512 thr, LDS ~57.6KB.
//   ht = h + s_c (n'-quarter); S2[n'][e] = select_k( (ht*a_k) . edge^T ), leaky, NEG
//   row softmax over e; P2T bf16; r = P2T . ehT; h_next=r; out (+)= r
// ---------------------------------------------------------------------------
template <bool WRITE_NEXT, bool ACC>
__global__ __launch_bounds__(512, 4) void k_e2n(
    const float* __restrict__ h, const float* __restrict__ s_c,
    const float* __restrict__ Hm, const float* __restrict__ a0,
    const float* __restrict__ a1, const float* __restrict__ a2,
    const float* __restrict__ edge, float* __restrict__ h_next,
    float* __restrict__ out)
{
    __shared__ __align__(16) unsigned short eh[112 * 72];   // [e][d]; rows 100..111 zero. P2T alias.
    __shared__ __align__(16) unsigned short ehT[64 * 136];  // [d][e]; cols 100..135 zero
    __shared__ __align__(16) float S2[EH * 112];            // scores [n'_loc][e]
    __shared__ __align__(16) float ht[32 * 66];             // [n'_loc][d] f32; rows 25..31 zero
    __shared__ __align__(16) unsigned char kk2[112 * 32];   // [e][n'_loc]
    __shared__ __align__(16) float a_lds[3 * 68];

    unsigned short* P2T = eh;   // [32][136] hw

    const int b = blockIdx.y, n_base = blockIdx.x * EH;
    const int tid = threadIdx.x;
    const int wv = tid >> 6, ln = tid & 63, l15 = ln & 15, l4 = ln >> 4;

    // ---- A: stage + zero pads ----
    for (int g = tid; g < 1600; g += 512) {
        const int e = g >> 4, d0 = (g & 15) * 4;
        const float4 v = ld4(&edge[(b * E_ + e) * D_ + d0]);
        unsigned short q[4] = { f2bf(v.x), f2bf(v.y), f2bf(v.z), f2bf(v.w) };
        short4v p = { (short)q[0], (short)q[1], (short)q[2], (short)q[3] };
        *reinterpret_cast<short4v*>(&eh[e * 72 + d0]) = p;
        ehT[(d0 + 0) * 136 + e] = q[0]; ehT[(d0 + 1) * 136 + e] = q[1];
        ehT[(d0 + 2) * 136 + e] = q[2]; ehT[(d0 + 3) * 136 + e] = q[3];
    }
    for (int i = tid; i < 1536; i += 512) {
        const int e = 100 + (i >> 7), d = i & 127;
        if (d < 72) eh[e * 72 + d] = 0;
    }
    for (int i = tid; i < 4096; i += 512) {
        const int d = i >> 6, c = i & 63;
        if (c < 36) ehT[d * 136 + 100 + c] = 0;
    }
    for (int g = tid; g < 400; g += 512) {
        const int lnn = g >> 4, d0 = (g & 15) * 4;
        const float4 hv = ld4(&h[(b * N_ + n_base + lnn) * D_ + d0]);
        const float4 sc = ld4(&s_c[b * D_ + d0]);
        ht[lnn * 66 + d0 + 0] = hv.x + sc.x;
        ht[lnn * 66 + d0 + 1] = hv.y + sc.y;
        ht[lnn * 66 + d0 + 2] = hv.z + sc.z;
        ht[lnn * 66 + d0 + 3] = hv.w + sc.w;
    }
    for (int i = tid; i < 896; i += 512) {           // ht rows 25..31 = 0
        const int r = 25 + (i >> 7), c = i & 127;
        if (c < 66) ht[r * 66 + c] = 0.f;
    }
    if (tid < 192) {
        const int k = tid >> 6, d = tid & 63;
        a_lds[k * 68 + d] = (k == 0 ? a0 : k == 1 ? a1 : a2)[d];
    }
    for (int i = tid; i < 3584; i += 512) {
        const int e = i >> 5, lnn = i & 31;
        int v = 0;
        if (e < 100 && lnn < EH) v = (int)Hm[(b * N_ + n_base + lnn) * E_ + e];
        kk2[e * 32 + lnn] = (unsigned char)v;
    }
    __syncthreads();

    // ---- C2: S2[n'][e]. M=n' (2 tiles), N=e (7 tiles). A=ht*a_k reg-built ----
    {
        const int Mt = wv >> 2, NtB = (wv & 3) * 2;
        const int ntiles = (NtB == 6) ? 1 : 2;
        f32x4 acc[3][2];
        #pragma unroll
        for (int k = 0; k < 3; ++k)
            #pragma unroll
            for (int j = 0; j < 2; ++j) { f32x4 z = { 0,0,0,0 }; acc[k][j] = z; }
        const int arow = Mt * 16 + l15;
        #pragma unroll
        for (int ks = 0; ks < 2; ++ks) {
            const int ko = ks * 32 + l4 * 8;
            short8 bf[2];
            #pragma unroll
            for (int j = 0; j < 2; ++j)
                if (j < ntiles)
                    bf[j] = *reinterpret_cast<const short8*>(&eh[((NtB + j) * 16 + l15) * 72 + ko]);
            float ev[8];
            #pragma unroll
            for (int jj = 0; jj < 8; ++jj) ev[jj] = ht[arow * 66 + ko + jj];
            #pragma unroll
            for (int k = 0; k < 3; ++k) {
                short8 ah, al;
                #pragma unroll
                for (int jj = 0; jj < 8; ++jj) {
                    const float w = ev[jj] * a_lds[k * 68 + ko + jj];
                    const unsigned short hi = f2bf(w);
                    ah[jj] = (short)hi;
                    al[jj] = (short)f2bf(w - bf2f(hi));
                }
                #pragma unroll
                for (int j = 0; j < 2; ++j)
                    if (j < ntiles) {
                        acc[k][j] = MFMA(ah, bf[j], acc[k][j]);
                        acc[k][j] = MFMA(al, bf[j], acc[k][j]);
                    }
            }
        }
        #pragma unroll
        for (int j = 0; j < 2; ++j)
            if (j < ntiles) {
                const int e = (NtB + j) * 16 + l15;
                const int n0 = Mt * 16 + l4 * 4;
                const unsigned kw = *reinterpret_cast<const unsigned*>(&kk2[e * 32 + n0]);
                #pragma unroll
                for (int r = 0; r < 4; ++r) {
                    const int nr = n0 + r;
                    if (nr < EH) {
                        const int kv = (kw >> (8 * r)) & 255;
                        float v = (kv == 1) ? acc[0][j][r] : (kv == 2) ? acc[1][j][r] : acc[2][j][r];
                        v = (v >= 0.f) ? v : LALPHA * v;
                        S2[nr * 112 + e] = kv ? v : NEGV;
                    }
                }
            }
    }
    __syncthreads();

    // ---- D2: row softmax over e + P2T quantize ----
    {
        const int e1 = ln, e2 = ln + 64;
        #pragma unroll
        for (int t = 0; t < 4; ++t) {
            const int nr = wv + 8 * t;
            if (nr < EH) {
                const float s1 = S2[nr * 112 + e1];
                const float s2 = (e2 < 100) ? S2[nr * 112 + e2] : -INFINITY;
                float mx = fmaxf(s1, s2);
                #pragma unroll
                for (int off = 32; off; off >>= 1) mx = fmaxf(mx, __shfl_xor(mx, off));
                const float p1 = __expf(s1 - mx);
                const float p2 = (e2 < 100) ? __expf(s2 - mx) : 0.f;
                float sum = p1 + p2;
                #pragma unroll
                for (int off = 32; off; off >>= 1) sum += __shfl_xor(sum, off);
                const float inv = 1.f / sum;
                P2T[nr * 136 + e1] = f2bf(p1 * inv);
                P2T[nr * 136 + e2] = (e2 < 100) ? f2bf(p2 * inv) : (unsigned short)0;
            }
        }
    }
    __syncthreads();

    // ---- Out: r = P2T . ehT. M=n' (2 tiles), N=d (4 tiles) ----
    {
        const int Mt = wv >> 2, Nt = wv & 3;
        f32x4 acc = { 0,0,0,0 };
        #pragma unroll
        for (int ks = 0; ks < 4; ++ks) {
            const int ko = ks * 32 + l4 * 8;
            short8 af = *reinterpret_cast<const short8*>(&P2T[(Mt * 16 + l15) * 136 + ko]);
            short8 bf = *reinterpret_cast<const short8*>(&ehT[(Nt * 16 + l15) * 136 + ko]);
            acc = MFMA(af, bf, acc);
        }
        #pragma unroll
        for (int r = 0; r < 4; ++r) {
            const int nr = Mt * 16 + l4 * 4 + r;
            if (nr < EH) {
                const int idx = (b * N_ + n_base + nr) * D_ + Nt * 16 + l15;
                const float v = acc[r];
                if (WRITE_NEXT) h_next[idx] = v;
                if (ACC) out[idx] += v; else out[idx] = v;
            }
        }
    }
}

extern "C" void kernel_launch(void* const* d_in, const int* in_sizes, int n_in,
                              void* d_out, int out_size, void* d_ws, size_t ws_size,
                              hipStream_t stream) {
    const float* hidden = (const float*)d_in[0];
    const float* Hm     = (const float*)d_in[1];
    const float* s_c    = (const float*)d_in[2];
    const float* a10    = (const float*)d_in[3];
    const float* a11    = (const float*)d_in[4];
    const float* a12    = (const float*)d_in[5];
    const float* a20    = (const float*)d_in[6];
    const float* a21    = (const float*)d_in[7];
    const float* a22    = (const float*)d_in[8];
    float* out = (float*)d_out;

    float* edge  = (float*)d_ws;
    float* hnext = edge + (size_t)B_ * E_ * D_;

    const dim3 grid(4, B_);

    k_n2e<<<grid, 512, 0, stream>>>(hidden, Hm, a10, a11, a12, edge);
    k_e2n<true, false><<<grid, 512, 0, stream>>>(hidden, s_c, Hm, a20, a21, a22, edge, hnext, out);
    k_n2e<<<grid, 512, 0, stream>>>(hnext, Hm, a10, a11, a12, edge);
    k_e2n<false, true><<<grid, 512, 0, stream>>>(hnext, s_c, Hm, a20, a21, a22, edge, nullptr, out);
}